// Round 2
// baseline (2323.834 us; speedup 1.0000x reference)
//
#include <hip/hip_runtime.h>
#include <hip/hip_bf16.h>

#define B_ 128
#define S_ 128
#define I_ 300
#define IP_ 320          // padded embed width
#define H_ 1024
#define K_ 1344          // IP_ + H_
#define C_ 2

typedef __attribute__((ext_vector_type(8))) short short8;
typedef __attribute__((ext_vector_type(4))) float f32x4;

// ---------------------------------------------------------------------------
// prep: Wcat bf16 [4096][1344] = [W_ih | pad0 | W_hh], from fp32 inputs
// ---------------------------------------------------------------------------
__global__ __launch_bounds__(256) void prep_weights(
    const float* __restrict__ W_ih,   // [4096,300] fp32
    const float* __restrict__ W_hh,   // [4096,1024] fp32
    __hip_bfloat16* __restrict__ Wcat)
{
    int idx = blockIdx.x * 256 + threadIdx.x;
    if (idx >= 4 * H_ * K_) return;
    int row = idx / K_;
    int k   = idx - row * K_;
    float v;
    if (k < IP_)
        v = (k < I_) ? W_ih[row * I_ + k] : 0.f;
    else
        v = W_hh[row * H_ + (k - IP_)];
    Wcat[idx] = __float2bfloat16(v);
}

__global__ __launch_bounds__(256) void prep_bias(
    const float* __restrict__ b_ih, const float* __restrict__ b_hh,
    float* __restrict__ bias)
{
    int i = blockIdx.x * 256 + threadIdx.x;
    if (i < 4 * H_) bias[i] = b_ih[i] + b_hh[i];
}

// xe bf16 [S][B][IP_]: gathered embedding rows, zero-padded 300..319
__global__ __launch_bounds__(256) void prep_xe(
    const int* __restrict__ x,              // [B,S]
    const float* __restrict__ embed_W,      // [V,300] fp32
    __hip_bfloat16* __restrict__ xe)
{
    int idx = blockIdx.x * 256 + threadIdx.x;
    if (idx >= S_ * B_ * IP_) return;
    int k  = idx % IP_;
    int tb = idx / IP_;          // t*B_ + b
    int b  = tb % B_;
    int t  = tb / B_;
    int row = x[b * S_ + t];
    float v = (k < I_) ? embed_W[(size_t)row * I_ + k] : 0.f;
    xe[idx] = __float2bfloat16(v);
}

// ---------------------------------------------------------------------------
// Per-timestep fused kernel: gates GEMM (MFMA bf16) + LSTM cell update.
//   A [128 x 1344] : cols 0..319 = xe[t], cols 320.. = h_prev (bf16)
//   B = Wcat [4096 x 1344], gate-major rows
//   block tile: 32 batch x 16 units x 4 gates; grid (64,4); 256 thr = 4 waves
// ---------------------------------------------------------------------------
__global__ __launch_bounds__(256) void lstm_step(
    const __hip_bfloat16* __restrict__ xe,    // [S,B,IP_]
    const __hip_bfloat16* __restrict__ Wcat,  // [4096,K_]
    const float* __restrict__ bias,           // [4096]
    float* __restrict__ c_state,              // [B,H] fp32
    __hip_bfloat16* __restrict__ hs,          // [S+1,B,H]
    int t)
{
    const int tid  = threadIdx.x;
    const int wid  = tid >> 6;
    const int lane = tid & 63;
    const int n0   = blockIdx.x * 16;   // hidden-unit group base
    const int mg   = blockIdx.y;        // batch group (rows mg*32 ..)

    // row stride 40 shorts = 80 B = 5*16 B: rows stay 16B-aligned for
    // ds_read_b128 and start banks cycle with period 8 -> 2-way only (free).
    __shared__ alignas(16) unsigned short As[32][40];
    __shared__ alignas(16) unsigned short Bs[64][40];
    __shared__ float Gs[32][65];

    const __hip_bfloat16* hprev = hs + (size_t)t * (B_ * H_);
    const __hip_bfloat16* xet   = xe + (size_t)t * (B_ * IP_);

    f32x4 acc0 = {0.f, 0.f, 0.f, 0.f};
    f32x4 acc1 = {0.f, 0.f, 0.f, 0.f};

    // A staging: thread -> row ar (0..31), 4 cols at ac.
    const int ar = tid >> 3;
    const int ac = (tid & 7) * 4;
    const int ab = mg * 32 + ar;              // batch index
    // B staging: thread -> row bj (0..63), 8 cols at bc0 (one 16B load).
    const int bj = tid >> 2;
    const int brow = (bj >> 4) * H_ + n0 + (bj & 15);   // row of Wcat
    const int bc0 = (tid & 3) * 8;
    const __hip_bfloat16* wrow = Wcat + (size_t)brow * K_;

    for (int ci = 0; ci < 42; ++ci) {
        __syncthreads();
        // ---- stage A tile [32 x 32] ----
        if (ci < 10) {
            *(short4*)&As[ar][ac] =
                *(const short4*)(xet + (size_t)ab * IP_ + ci * 32 + ac);
        } else {
            *(short4*)&As[ar][ac] =
                *(const short4*)(hprev + (size_t)ab * H_ + (ci - 10) * 32 + ac);
        }
        // ---- stage B tile [64 x 32] ----
        *(short8*)&Bs[bj][bc0] = *(const short8*)(wrow + ci * 32 + bc0);
        __syncthreads();
        // ---- MFMA: wave w owns gate w (Bs rows w*16..w*16+15) ----
        const int fr = lane & 15;
        const int fq = lane >> 4;
        short8 a0 = *(const short8*)&As[fr][fq * 8];
        short8 a1 = *(const short8*)&As[16 + fr][fq * 8];
        short8 b  = *(const short8*)&Bs[wid * 16 + fr][fq * 8];
        acc0 = __builtin_amdgcn_mfma_f32_16x16x32_bf16(a0, b, acc0, 0, 0, 0);
        acc1 = __builtin_amdgcn_mfma_f32_16x16x32_bf16(a1, b, acc1, 0, 0, 0);
    }

    // scatter accumulators: Gs[m][g*16+u]   (C/D: col=lane&15, row=q*4+r)
    {
        const int col = wid * 16 + (lane & 15);
        const int rbase = (lane >> 4) * 4;
#pragma unroll
        for (int r = 0; r < 4; ++r) {
            Gs[rbase + r][col]      = acc0[r];
            Gs[16 + rbase + r][col] = acc1[r];
        }
    }
    __syncthreads();

    // LSTM cell update: 512 (m,u) elements, 2 per thread. Gate order i,f,g,o.
#pragma unroll
    for (int e = tid; e < 512; e += 256) {
        int m = e >> 4;
        int u = e & 15;
        int n = n0 + u;
        int b = mg * 32 + m;
        float gi = Gs[m][u]      + bias[n];
        float gf = Gs[m][16 + u] + bias[H_ + n];
        float gg = Gs[m][32 + u] + bias[2 * H_ + n];
        float go = Gs[m][48 + u] + bias[3 * H_ + n];
        float si = 1.f / (1.f + __expf(-gi));
        float sf = 1.f / (1.f + __expf(-gf));
        float so = 1.f / (1.f + __expf(-go));
        float tg = tanhf(gg);
        size_t off = (size_t)b * H_ + n;
        float c_new = sf * c_state[off] + si * tg;
        c_state[off] = c_new;
        float h_new = so * tanhf(c_new);
        hs[(size_t)(t + 1) * (B_ * H_) + off] = __float2bfloat16(h_new);
    }
}

// ---------------------------------------------------------------------------
// Head: one wave per (b,t): out = h . lin_W^T + lin_b, masked by lengths.
// ---------------------------------------------------------------------------
__global__ __launch_bounds__(256) void final_linear(
    const __hip_bfloat16* __restrict__ hs,   // [S+1,B,H]
    const float* __restrict__ lin_W,         // [2,H] fp32
    const float* __restrict__ lin_b,         // [2] fp32
    const int* __restrict__ lengths,         // [B]
    float* __restrict__ out)                 // [B*S, 2] fp32
{
    const int wid  = threadIdx.x >> 6;
    const int lane = threadIdx.x & 63;
    const int p = blockIdx.x * 4 + wid;      // b*S + t
    const int b = p >> 7;
    const int t = p & 127;
    const __hip_bfloat16* h =
        hs + (size_t)(t + 1) * (B_ * H_) + (size_t)b * H_;
    float s0 = 0.f, s1 = 0.f;
#pragma unroll
    for (int i = 0; i < 16; ++i) {
        int n = lane + 64 * i;
        float hv = __bfloat162float(h[n]);
        s0 += hv * lin_W[n];
        s1 += hv * lin_W[H_ + n];
    }
#pragma unroll
    for (int off = 32; off > 0; off >>= 1) {
        s0 += __shfl_down(s0, off);
        s1 += __shfl_down(s1, off);
    }
    if (lane == 0) {
        float* o = out + (size_t)p * 2;
        if (t < lengths[b]) {
            o[0] = s0 + lin_b[0];
            o[1] = s1 + lin_b[1];
        } else {
            o[0] = 1.0f;
            o[1] = 0.0f;
        }
    }
}

extern "C" void kernel_launch(void* const* d_in, const int* in_sizes, int n_in,
                              void* d_out, int out_size, void* d_ws,
                              size_t ws_size, hipStream_t stream) {
    const int* x              = (const int*)d_in[0];
    const int* lengths        = (const int*)d_in[1];
    const float* embed_W      = (const float*)d_in[2];
    const float* W_ih         = (const float*)d_in[3];
    const float* W_hh         = (const float*)d_in[4];
    const float* b_ih         = (const float*)d_in[5];
    const float* b_hh         = (const float*)d_in[6];
    const float* lin_W        = (const float*)d_in[7];
    const float* lin_b        = (const float*)d_in[8];
    float* out                = (float*)d_out;

    // workspace layout (bytes, 256-aligned):
    //   c_state fp32 [B,H]            @ 0          (524288)
    //   hs bf16 [S+1,B,H]             @ 524288     (33816576)
    //   Wcat bf16 [4096,1344]         @ 34340864   (11010048)
    //   bias fp32 [4096]              @ 45350912   (16384)
    //   xe bf16 [S,B,320]             @ 45367296   (10485760)
    char* ws = (char*)d_ws;
    float* c_state        = (float*)(ws + 0);
    __hip_bfloat16* hs    = (__hip_bfloat16*)(ws + 524288);
    __hip_bfloat16* Wcat  = (__hip_bfloat16*)(ws + 34340864);
    float* bias           = (float*)(ws + 45350912);
    __hip_bfloat16* xe    = (__hip_bfloat16*)(ws + 45367296);

    prep_weights<<<(4 * H_ * K_ + 255) / 256, 256, 0, stream>>>(W_ih, W_hh, Wcat);
    prep_bias<<<(4 * H_ + 255) / 256, 256, 0, stream>>>(b_ih, b_hh, bias);
    prep_xe<<<(S_ * B_ * IP_ + 255) / 256, 256, 0, stream>>>(x, embed_W, xe);
    hipMemsetAsync(c_state, 0, (size_t)B_ * H_ * sizeof(float), stream);
    hipMemsetAsync(hs, 0, (size_t)B_ * H_ * sizeof(__hip_bfloat16), stream);

    for (int t = 0; t < S_; ++t) {
        lstm_step<<<dim3(64, 4), 256, 0, stream>>>(
            xe, Wcat, bias, c_state, hs, t);
    }
    final_linear<<<dim3((B_ * S_) / 4), 256, 0, stream>>>(
        hs, lin_W, lin_b, lengths, out);
}